// Round 12
// baseline (38.308 us; speedup 1.0000x reference)
//
#include <hip/hip_runtime.h>
#include <hip/hip_bf16.h>
#include <stdint.h>

#define NN 8192
#define HH 256
#define GG 256

typedef __bf16 bf16x8 __attribute__((ext_vector_type(8)));
typedef float f32x4 __attribute__((ext_vector_type(4)));
typedef unsigned short u16v8 __attribute__((ext_vector_type(8)));

__device__ __forceinline__ ushort f2bf(float f) {
  union { float f; uint32_t u; } v; v.f = f;
  uint32_t u = v.u;
  u += 0x7fffu + ((u >> 16) & 1u);   // RNE
  return (ushort)(u >> 16);
}
__device__ __forceinline__ float bf2f(ushort h) {
  union { uint32_t u; float f; } v; v.u = ((uint32_t)h) << 16;
  return v.f;
}

// ---------------- prep ----------------
// p1w/p2w/aw (f32 [k][n]) -> bf16 K-SLAB layout, pre-swizzled:
//   ushort idx(col,k) = (k>>6)*16384 + col*64 + (((k>>3)&7)^(col&7))*8 + (k&7)
// (slab ks = 32KB = all 256 cols x 64 k, chunk-swizzled within each col row)
// r1w/r2w -> elementwise bf16 [k][n].
__global__ __launch_bounds__(512) void k_prep(const float* __restrict__ p1w,
                                              const float* __restrict__ p2w,
                                              const float* __restrict__ aw,
                                              const float* __restrict__ r1w,
                                              const float* __restrict__ r2w,
                                              ushort* __restrict__ wT1,
                                              ushort* __restrict__ wT2,
                                              ushort* __restrict__ wTa,
                                              ushort* __restrict__ rK1,
                                              ushort* __restrict__ rK2) {
  int b = blockIdx.x, t = threadIdx.x;
  if (b < 48) {
    int mat = b >> 4, tile = b & 15;
    int tr = (tile >> 2) * 64, tc = (tile & 3) * 64;   // tr = k-range, tc = n-range
    const float* w = mat == 0 ? p1w : mat == 1 ? p2w : aw;
    ushort* o = mat == 0 ? wT1 : mat == 1 ? wT2 : wTa;
    __shared__ float tileb[64][65];
    int rr = t >> 3, cg = (t & 7) * 8;
    const float* src = w + (size_t)(tr + rr) * HH + tc + cg;
    float4 v0 = *(const float4*)src;
    float4 v1 = *(const float4*)(src + 4);
    float* drow = &tileb[rr][cg];
    drow[0] = v0.x; drow[1] = v0.y; drow[2] = v0.z; drow[3] = v0.w;
    drow[4] = v1.x; drow[5] = v1.y; drow[6] = v1.z; drow[7] = v1.w;
    __syncthreads();
    int rn = t >> 3, kg = (t & 7) * 8;   // col = tc+rn, k = tr+kg..+7 (one chunk)
    u16v8 a;
#pragma unroll
    for (int j = 0; j < 8; ++j) a[j] = f2bf(tileb[kg + j][rn]);
    int col = tc + rn;
    size_t idx = (size_t)(tr >> 6) * 16384 + (size_t)col * 64 +
                 (size_t)((((kg >> 3) & 7) ^ (col & 7)) * 8);
    *(u16v8*)(o + idx) = a;
  } else {
    int eb = b - 48;
    const float* src = (eb < 8) ? r1w : r2w;
    ushort* dst = (eb < 8) ? rK1 : rK2;
    int sub = eb & 7;
#pragma unroll
    for (int it = 0; it < 2; ++it) {
      int base = sub * 8192 + it * 4096 + t * 8;
      float4 v0 = *(const float4*)(src + base);
      float4 v1 = *(const float4*)(src + base + 4);
      u16v8 o;
      o[0] = f2bf(v0.x); o[1] = f2bf(v0.y); o[2] = f2bf(v0.z); o[3] = f2bf(v0.w);
      o[4] = f2bf(v1.x); o[5] = f2bf(v1.y); o[6] = f2bf(v1.z); o[7] = f2bf(v1.w);
      *(u16v8*)(dst + base) = o;
    }
  }
}

// 32 KB slab load: linear (source pre-swizzled), 4 chunks/thread at 512 thr
#define LOADSLAB(SRC, DST)                                                     \
  {                                                                            \
    _Pragma("unroll")                                                          \
    for (int i_ = 0; i_ < 4; ++i_) {                                           \
      int ch_ = i_ * 512 + tid;                                                \
      __builtin_amdgcn_global_load_lds(                                        \
          (const __attribute__((address_space(1))) uint32_t*)((SRC) + ch_ * 8),\
          (__attribute__((address_space(3))) uint32_t*)((DST) + ch_ * 8),      \
          16, 0, 0);                                                           \
    }                                                                          \
  }

// ---------------- phi: 512 blocks x 16 rows, 2 blocks/CU, K-split stages ----
// Per layer: 4 k-stages of 32KB weight slab (double-buffered); acc in regs.
// act: single 8 KB buffer [16 rows][256 k] bf16, chunk-swizzled c^(r&7).
// Outputs: hb linear bf16 [8192][256]; sb row-swizzled bf16 (chunk c at c^(r&7)).
__global__ __launch_bounds__(512) void k_phi(
    const float* __restrict__ x,
    const float* __restrict__ ab, const float* __restrict__ p1b,
    const float* __restrict__ p2b,
    const ushort* __restrict__ wT1, const ushort* __restrict__ wT2,
    const ushort* __restrict__ wTa,
    ushort* __restrict__ hb, ushort* __restrict__ sb) {
  __shared__ ushort s0[16384];   // 32 KB
  __shared__ ushort s1[16384];   // 32 KB
  __shared__ ushort act[4096];   // 8 KB
  const int tid = threadIdx.x;
  const int rowbase = blockIdx.x * 16;
  const int lane = tid & 63, wid = tid >> 6;   // 8 waves
  const int l15 = lane & 15, q = lane >> 4;
  const int cw = wid * 32;                      // wave's 32-col strip

  LOADSLAB(wT1, s0);                            // slab s=0 prefetch

  {  // stage x: one 16B chunk per thread (16 rows x 32 chunks = 512)
    int row = tid >> 5, c = tid & 31;
    const float* xp = x + (size_t)(rowbase + row) * HH + c * 8;
    float4 v0 = *(const float4*)xp;
    float4 v1 = *(const float4*)(xp + 4);
    u16v8 o;
    o[0] = f2bf(v0.x); o[1] = f2bf(v0.y); o[2] = f2bf(v0.z); o[3] = f2bf(v0.w);
    o[4] = f2bf(v1.x); o[5] = f2bf(v1.y); o[6] = f2bf(v1.z); o[7] = f2bf(v1.w);
    int dst = (tid & ~31) | (c ^ (row & 7));
    *(u16v8*)(act + dst * 8) = o;
  }
  __syncthreads();   // x staged + slab0 landed

  for (int L = 0; L < 3; ++L) {
    f32x4 acc0 = {0.f, 0.f, 0.f, 0.f}, acc1 = acc0;
#pragma unroll
    for (int ks = 0; ks < 4; ++ks) {
      const int s = L * 4 + ks;
      const ushort* cur = (s & 1) ? s1 : s0;
      if (s < 11) {                       // prefetch next slab into other buf
        const int sn = s + 1;
        const ushort* wtn = (sn >> 2) == 0 ? wT1 : (sn >> 2) == 1 ? wT2 : wTa;
        ushort* dstb = (sn & 1) ? s1 : s0;
        LOADSLAB(wtn + (sn & 3) * 16384, dstb);
      }
#pragma unroll
      for (int kk = 0; kk < 2; ++kk) {
        int c3 = kk * 4 + q;              // low-3 chunk bits within slab/act
        int ca = (ks * 8 + c3) ^ (l15 & 7);
        bf16x8 a = *(const bf16x8*)(act + (l15 * 32 + ca) * 8);
        int col0 = cw + l15, col1 = cw + 16 + l15;
        bf16x8 b0 = *(const bf16x8*)(cur + col0 * 64 + ((c3 ^ (col0 & 7)) * 8));
        bf16x8 b1 = *(const bf16x8*)(cur + col1 * 64 + ((c3 ^ (col1 & 7)) * 8));
        acc0 = __builtin_amdgcn_mfma_f32_16x16x32_bf16(a, b0, acc0, 0, 0, 0);
        acc1 = __builtin_amdgcn_mfma_f32_16x16x32_bf16(a, b1, acc1, 0, 0, 0);
      }
      __syncthreads();   // cur consumed everywhere + prefetch landed
    }
    // layer-end writeback (all act reads for this layer completed pre-barrier)
    const float* bias = (L == 0) ? p1b : (L == 1) ? p2b : ab;
#pragma unroll
    for (int nt = 0; nt < 2; ++nt) {
      f32x4 acc = nt ? acc1 : acc0;
      int col = cw + nt * 16 + l15;
      float bv = bias[col];
#pragma unroll
      for (int i = 0; i < 4; ++i) {
        float vv = acc[i] + bv;
        int r = q * 4 + i;
        if (L < 2) {
          vv = fmaxf(vv, 0.f);
          act[(r * 32 + ((col >> 3) ^ (r & 7))) * 8 + (col & 7)] = f2bf(vv);
          if (L == 1) hb[(size_t)(rowbase + r) * HH + col] = f2bf(vv);
        } else {
          // s: row-swizzled global ((rowbase+r)&7 == r&7 since rowbase%16==0)
          sb[(size_t)(rowbase + r) * HH + ((col >> 3) ^ (r & 7)) * 8 + (col & 7)] =
              f2bf(vv);
        }
      }
    }
    __syncthreads();   // act writes visible before next layer reads
  }
}

// ---------------- attn + aggregation + rho, one block per graph -------------
__global__ __launch_bounds__(256) void k_attn(
    const ushort* __restrict__ sb, const ushort* __restrict__ hb,
    const int* __restrict__ batch,
    const ushort* __restrict__ rK1, const ushort* __restrict__ rK2,
    const float* __restrict__ r1b, const float* __restrict__ r2b,
    float* __restrict__ out) {
  __shared__ ushort st[64 * 256];   // 32 KB staged s rows (swizzled per global row)
  __shared__ float colw[256];
  __shared__ float xa[256];
  __shared__ float t1[256];
  __shared__ int bb[256];
  __shared__ int mm[4];
  const int g = blockIdx.x, tid = threadIdx.x;

  // ---- row-range search (2-round parallel lower_bound) ----
  bb[tid] = batch[tid * 32];
  if (tid == 0) { mm[0] = 256; mm[1] = 256; }
  __syncthreads();
  {
    int v = bb[tid];
    int pv = (tid == 0) ? -1 : bb[tid - 1];
    if (v >= g && pv < g) mm[0] = tid;
    if (v >= g + 1 && pv < g + 1) mm[1] = tid;
  }
  __syncthreads();
  {
    int which = -1, v = 0;
    if (tid < 32) { which = 2; v = g; }
    else if (tid >= 64 && tid < 96) { which = 3; v = g + 1; }
    if (which >= 0) {
      int B = mm[which - 2];
      int u = tid & 31;
      if (B == 0) { if (u == 0) mm[which] = 0; }
      else {
        int i = (B - 1) * 32 + 1 + u;
        if (i <= 8191 && batch[i] >= v && batch[i - 1] < v) mm[which] = i;
        if (B == 256 && u == 0 && batch[8191] < v) mm[which] = 8192;
      }
    }
  }
  __syncthreads();
  const int r0 = mm[2];
  int n = mm[3] - r0;
  colw[tid] = 0.f;
  const int lane = tid & 63, wid = tid >> 6;
  const int l15 = lane & 15, q = lane >> 4;
  const int x7g = (r0 + l15) & 7;    // swizzle key: global row (r0+16a+l15)&7

  if (n <= 64) {
    // stage: straight linear copy (sb rows carry their own swizzle)
    for (int ch = tid; ch < n * 32; ch += 256)
      __builtin_amdgcn_global_load_lds(
          (const __attribute__((address_space(1))) uint32_t*)(sb + ((size_t)r0 * 32 + ch) * 8),
          (__attribute__((address_space(3))) uint32_t*)(st + ch * 8),
          16, 0, 0);
    __syncthreads();
    const char* stc = (const char*)st;
    if (wid * 16 < n) {
      f32x4 acc0 = {0.f, 0.f, 0.f, 0.f};
      f32x4 acc1 = acc0, acc2 = acc0, acc3 = acc0;
      const int arow = wid * 16 + l15;
#pragma unroll
      for (int kk = 0; kk < 8; kk++) {
        int kc = ((kk * 4 + q) ^ x7g) << 4;
        bf16x8 a  = *(const bf16x8*)(stc + arow * 512 + kc);
        bf16x8 b0 = *(const bf16x8*)(stc + l15 * 512 + kc);
        acc0 = __builtin_amdgcn_mfma_f32_16x16x32_bf16(a, b0, acc0, 0, 0, 0);
        if (n > 16) {
          bf16x8 b1 = *(const bf16x8*)(stc + (16 + l15) * 512 + kc);
          acc1 = __builtin_amdgcn_mfma_f32_16x16x32_bf16(a, b1, acc1, 0, 0, 0);
        }
        if (n > 32) {
          bf16x8 b2 = *(const bf16x8*)(stc + (32 + l15) * 512 + kc);
          acc2 = __builtin_amdgcn_mfma_f32_16x16x32_bf16(a, b2, acc2, 0, 0, 0);
        }
        if (n > 48) {
          bf16x8 b3 = *(const bf16x8*)(stc + (48 + l15) * 512 + kc);
          acc3 = __builtin_amdgcn_mfma_f32_16x16x32_bf16(a, b3, acc3, 0, 0, 0);
        }
      }
      float mi[4], e0[4], e1[4], e2[4], e3[4], inv[4];
#pragma unroll
      for (int i = 0; i < 4; i++) {
        float mmx = (l15 < n) ? acc0[i] : -1e30f;
        if (16 + l15 < n) mmx = fmaxf(mmx, acc1[i]);
        if (32 + l15 < n) mmx = fmaxf(mmx, acc2[i]);
        if (48 + l15 < n) mmx = fmaxf(mmx, acc3[i]);
        mi[i] = mmx;
      }
#pragma unroll
      for (int off = 1; off < 16; off <<= 1)
#pragma unroll
        for (int i = 0; i < 4; i++) mi[i] = fmaxf(mi[i], __shfl_xor(mi[i], off));
#pragma unroll
      for (int i = 0; i < 4; i++) {
        e0[i] = (l15 < n)      ? __expf(acc0[i] - mi[i]) : 0.f;
        e1[i] = (16 + l15 < n) ? __expf(acc1[i] - mi[i]) : 0.f;
        e2[i] = (32 + l15 < n) ? __expf(acc2[i] - mi[i]) : 0.f;
        e3[i] = (48 + l15 < n) ? __expf(acc3[i] - mi[i]) : 0.f;
        inv[i] = e0[i] + e1[i] + e2[i] + e3[i];
      }
#pragma unroll
      for (int off = 1; off < 16; off <<= 1)
#pragma unroll
        for (int i = 0; i < 4; i++) inv[i] += __shfl_xor(inv[i], off);
#pragma unroll
      for (int i = 0; i < 4; i++) inv[i] = 1.f / inv[i];
      float cs[4];
#pragma unroll
      for (int t = 0; t < 4; t++) {
        const float* et = t == 0 ? e0 : t == 1 ? e1 : t == 2 ? e2 : e3;
        float c4 = 0.f;
#pragma unroll
        for (int i = 0; i < 4; i++) {
          int row = wid * 16 + q * 4 + i;
          c4 += (row < n) ? et[i] * inv[i] : 0.f;
        }
        cs[t] = c4;
      }
#pragma unroll
      for (int t = 0; t < 4; t++) {
        cs[t] += __shfl_xor(cs[t], 16);
        cs[t] += __shfl_xor(cs[t], 32);
      }
      if (lane < 16) {
#pragma unroll
        for (int t = 0; t < 4; t++)
          if (t * 16 < n) atomicAdd(&colw[t * 16 + l15], cs[t]);
      }
    }
    __syncthreads();
  } else {
    // fallback (never taken for this input): swizzle-aware global dots
    int nnn = n > 256 ? 256 : n;
    __syncthreads();
    for (int i = wid; i < nnn; i += 4) {
      int ra = r0 + i;
      const ushort* pa = sb + (size_t)ra * HH;
      float d[4]; int j4[4];
#pragma unroll
      for (int u = 0; u < 4; u++) {
        j4[u] = lane + u * 64;
        d[u] = -1e30f;
        if (j4[u] < nnn) {
          int rb = r0 + j4[u];
          const ushort* pb = sb + (size_t)rb * HH;
          float acc = 0.f;
          for (int c = 0; c < 32; ++c) {
            int ca = c ^ (ra & 7), cb = c ^ (rb & 7);
#pragma unroll
            for (int e = 0; e < 8; ++e)
              acc = fmaf(bf2f(pa[ca * 8 + e]), bf2f(pb[cb * 8 + e]), acc);
          }
          d[u] = acc;
        }
      }
      float m = fmaxf(fmaxf(d[0], d[1]), fmaxf(d[2], d[3]));
#pragma unroll
      for (int off = 32; off; off >>= 1) m = fmaxf(m, __shfl_xor(m, off));
      float e[4], ss = 0.f;
#pragma unroll
      for (int u = 0; u < 4; u++) { e[u] = (j4[u] < nnn) ? __expf(d[u] - m) : 0.f; ss += e[u]; }
#pragma unroll
      for (int off = 32; off; off >>= 1) ss += __shfl_xor(ss, off);
      float iv = 1.f / ss;
#pragma unroll
      for (int u = 0; u < 4; u++)
        if (j4[u] < nnn) atomicAdd(&colw[j4[u]], e[u] * iv);
    }
    __syncthreads();
  }

  // ---- aggregation: xa[c] = sum_j colw[j] * h[r0+j][c] ----
  {
    int nn = n > 256 ? 256 : n;
    float agg = 0.f;
#pragma unroll 4
    for (int j = 0; j < nn; ++j)
      agg = fmaf(colw[j], bf2f(hb[(size_t)(r0 + j) * HH + tid]), agg);
    xa[tid] = agg;
  }
  __syncthreads();

  // ---- rho GEMV: out[g] = relu(relu(xa@r1w+b1)@r2w+b2) ----
  {
    float a0 = 0.f, a1 = 0.f, a2 = 0.f, a3 = 0.f;
    const ushort* wp = rK1 + tid;
#pragma unroll 8
    for (int k = 0; k < HH; k += 4) {
      a0 = fmaf(xa[k],     bf2f(wp[(size_t)(k)     * HH]), a0);
      a1 = fmaf(xa[k + 1], bf2f(wp[(size_t)(k + 1) * HH]), a1);
      a2 = fmaf(xa[k + 2], bf2f(wp[(size_t)(k + 2) * HH]), a2);
      a3 = fmaf(xa[k + 3], bf2f(wp[(size_t)(k + 3) * HH]), a3);
    }
    t1[tid] = fmaxf(r1b[tid] + (a0 + a1) + (a2 + a3), 0.f);
    __syncthreads();
    a0 = a1 = a2 = a3 = 0.f;
    const ushort* wp2 = rK2 + tid;
#pragma unroll 8
    for (int k = 0; k < HH; k += 4) {
      a0 = fmaf(t1[k],     bf2f(wp2[(size_t)(k)     * HH]), a0);
      a1 = fmaf(t1[k + 1], bf2f(wp2[(size_t)(k + 1) * HH]), a1);
      a2 = fmaf(t1[k + 2], bf2f(wp2[(size_t)(k + 2) * HH]), a2);
      a3 = fmaf(t1[k + 3], bf2f(wp2[(size_t)(k + 3) * HH]), a3);
    }
    out[(size_t)g * HH + tid] = fmaxf(r2b[tid] + (a0 + a1) + (a2 + a3), 0.f);
  }
}

// ---------------- launcher ----------------
extern "C" void kernel_launch(void* const* d_in, const int* in_sizes, int n_in,
                              void* d_out, int out_size, void* d_ws, size_t ws_size,
                              hipStream_t stream) {
  const float* x   = (const float*)d_in[0];
  const int* batch = (const int*)d_in[1];
  const float* aw  = (const float*)d_in[3];
  const float* ab  = (const float*)d_in[4];
  const float* p1w = (const float*)d_in[5];
  const float* p1b = (const float*)d_in[6];
  const float* p2w = (const float*)d_in[7];
  const float* p2b = (const float*)d_in[8];
  const float* r1w = (const float*)d_in[9];
  const float* r1b = (const float*)d_in[10];
  const float* r2w = (const float*)d_in[11];
  const float* r2b = (const float*)d_in[12];
  float* out = (float*)d_out;

  char* ws = (char*)d_ws;
  ushort* hb  = (ushort*)(ws);                                  // 4 MB
  ushort* sb  = (ushort*)(ws + (size_t)4 * 1024 * 1024);        // 4 MB
  ushort* wT1 = (ushort*)(ws + (size_t)8 * 1024 * 1024);        // 128 KB each
  ushort* wT2 = wT1 + 65536;
  ushort* wTa = wT2 + 65536;
  ushort* rK1 = wTa + 65536;
  ushort* rK2 = rK1 + 65536;

  k_prep<<<dim3(64), dim3(512), 0, stream>>>(p1w, p2w, aw, r1w, r2w,
                                             wT1, wT2, wTa, rK1, rK2);
  k_phi<<<dim3(512), dim3(512), 0, stream>>>(x, ab, p1b, p2b,
                                             wT1, wT2, wTa, hb, sb);
  k_attn<<<dim3(256), dim3(256), 0, stream>>>(sb, hb, batch, rK1, rK2,
                                              r1b, r2b, out);
}

// Round 13
// 35.553 us; speedup vs baseline: 1.0775x; 1.0775x over previous
//
#include <hip/hip_runtime.h>
#include <hip/hip_bf16.h>
#include <stdint.h>

#define NN 8192
#define HH 256
#define GG 256

typedef __bf16 bf16x8 __attribute__((ext_vector_type(8)));
typedef float f32x4 __attribute__((ext_vector_type(4)));
typedef unsigned short u16v8 __attribute__((ext_vector_type(8)));

__device__ __forceinline__ ushort f2bf(float f) {
  union { float f; uint32_t u; } v; v.f = f;
  uint32_t u = v.u;
  u += 0x7fffu + ((u >> 16) & 1u);   // RNE
  return (ushort)(u >> 16);
}
__device__ __forceinline__ float bf2f(ushort h) {
  union { uint32_t u; float f; } v; v.u = ((uint32_t)h) << 16;
  return v.f;
}

// ---------------- prep: transpose p1w/p2w/aw -> bf16 [n][k]; convert r1w/r2w ----
__global__ __launch_bounds__(512) void k_prep(const float* __restrict__ p1w,
                                              const float* __restrict__ p2w,
                                              const float* __restrict__ aw,
                                              const float* __restrict__ r1w,
                                              const float* __restrict__ r2w,
                                              ushort* __restrict__ wT1,
                                              ushort* __restrict__ wT2,
                                              ushort* __restrict__ wTa,
                                              ushort* __restrict__ rK1,
                                              ushort* __restrict__ rK2) {
  int b = blockIdx.x, t = threadIdx.x;
  if (b < 48) {
    int mat = b >> 4, tile = b & 15;
    int tr = (tile >> 2) * 64, tc = (tile & 3) * 64;
    const float* w = mat == 0 ? p1w : mat == 1 ? p2w : aw;
    ushort* o = mat == 0 ? wT1 : mat == 1 ? wT2 : wTa;
    __shared__ float tileb[64][65];
    int rr = t >> 3, cg = (t & 7) * 8;
    const float* src = w + (size_t)(tr + rr) * HH + tc + cg;
    float4 v0 = *(const float4*)src;
    float4 v1 = *(const float4*)(src + 4);
    float* drow = &tileb[rr][cg];
    drow[0] = v0.x; drow[1] = v0.y; drow[2] = v0.z; drow[3] = v0.w;
    drow[4] = v1.x; drow[5] = v1.y; drow[6] = v1.z; drow[7] = v1.w;
    __syncthreads();
    int rn = t >> 3, kg = (t & 7) * 8;
    u16v8 a;
#pragma unroll
    for (int j = 0; j < 8; ++j) a[j] = f2bf(tileb[kg + j][rn]);
    *(u16v8*)(o + (size_t)(tc + rn) * HH + tr + kg) = a;
  } else {
    int eb = b - 48;
    const float* src = (eb < 8) ? r1w : r2w;
    ushort* dst = (eb < 8) ? rK1 : rK2;
    int sub = eb & 7;
#pragma unroll
    for (int it = 0; it < 2; ++it) {
      int base = sub * 8192 + it * 4096 + t * 8;
      float4 v0 = *(const float4*)(src + base);
      float4 v1 = *(const float4*)(src + base + 4);
      u16v8 o;
      o[0] = f2bf(v0.x); o[1] = f2bf(v0.y); o[2] = f2bf(v0.z); o[3] = f2bf(v0.w);
      o[4] = f2bf(v1.x); o[5] = f2bf(v1.y); o[6] = f2bf(v1.z); o[7] = f2bf(v1.w);
      *(u16v8*)(dst + base) = o;
    }
  }
}

// quarter loader: 32 KB, source chunk-swizzled (gload_lds writes linearly)
#define LOADQ(SRC, DST)                                                        \
  {                                                                            \
    _Pragma("unroll")                                                          \
    for (int it_ = 0; it_ < 2; ++it_) {                                        \
      int ch_ = it_ * 1024 + tid;                                              \
      int rw_ = ch_ >> 5, c_ = ch_ & 31;                                       \
      int sc_ = (ch_ & ~31) | (c_ ^ (rw_ & 7));                                \
      __builtin_amdgcn_global_load_lds(                                        \
          (const __attribute__((address_space(1))) uint32_t*)((SRC) + sc_ * 8),\
          (__attribute__((address_space(3))) uint32_t*)((DST) + ch_ * 8),      \
          16, 0, 0);                                                           \
    }                                                                          \
  }

// ---------------- main: one block per graph, counted-vmcnt phi pipeline ----
__global__ __launch_bounds__(1024) void k_main(
    const float* __restrict__ x, const int* __restrict__ batch,
    const float* __restrict__ ab,
    const float* __restrict__ p1b, const float* __restrict__ p2b,
    const float* __restrict__ r1b, const float* __restrict__ r2b,
    const ushort* __restrict__ wT1, const ushort* __restrict__ wT2,
    const ushort* __restrict__ wTa,
    const ushort* __restrict__ rK1, const ushort* __restrict__ rK2,
    float* __restrict__ out) {
  __shared__ char smem[139808];
  ushort* wq0  = (ushort*)smem;               // 32 KB
  ushort* wq1  = (ushort*)(smem + 32768);     // 32 KB
  ushort* actA = (ushort*)(smem + 65536);     // 32 KB
  ushort* actB = (ushort*)(smem + 98304);     // 32 KB
  int*    bb   = (int*)(smem + 131072);       // 256 ints
  int*    mm   = (int*)(smem + 132096);       // 4 ints
  float*  colw = (float*)(smem + 132128);     // 256 f
  float*  parts= (float*)(smem + 134176);     // 1024 f
  float*  pmax = (float*)(smem + 138272);     // 2*64 f
  float*  psum = (float*)(smem + 138784);     // 2*64 f
  float*  fct  = (float*)(smem + 139296);     // 2*64 f

  const int g = blockIdx.x, tid = threadIdx.x;
  const int lane = tid & 63, wid = tid >> 6;     // 16 waves
  const int l15 = lane & 15, q = lane >> 4, x7 = l15 & 7;

  // ---- row-range search ----
  if (tid < 256) bb[tid] = batch[tid * 32];
  if (tid == 0) { mm[0] = 256; mm[1] = 256; }
  __syncthreads();
  if (tid < 256) {
    int v = bb[tid];
    int pv = (tid == 0) ? -1 : bb[tid - 1];
    if (v >= g && pv < g) mm[0] = tid;
    if (v >= g + 1 && pv < g + 1) mm[1] = tid;
  }
  __syncthreads();
  {
    int which = -1, v = 0;
    if (tid < 32) { which = 2; v = g; }
    else if (tid >= 64 && tid < 96) { which = 3; v = g + 1; }
    if (which >= 0) {
      int B = mm[which - 2];
      int u = tid & 31;
      if (B == 0) { if (u == 0) mm[which] = 0; }
      else {
        int i = (B - 1) * 32 + 1 + u;
        if (i <= 8191 && batch[i] >= v && batch[i - 1] < v) mm[which] = i;
        if (B == 256 && u == 0 && batch[8191] < v) mm[which] = 8192;
      }
    }
  }
  __syncthreads();
  const int r0 = mm[2];
  int n = mm[3] - r0;
  if (n > 64) n = 64;
  const int nrt = (n + 15) >> 4;
  const int R = nrt * 16;

  // ---- prefetch slab 0 & 1, overlapped with x staging ----
  LOADQ(wT1, wq0);
  LOADQ(wT1 + 16384, wq1);

  for (int ch = tid; ch < R * 32; ch += 1024) {
    int row = ch >> 5, c = ch & 31;
    int srow = r0 + row; if (srow > 8191) srow = 8191;
    const float* xp = x + (size_t)srow * HH + c * 8;
    float4 v0 = *(const float4*)xp;
    float4 v1 = *(const float4*)(xp + 4);
    u16v8 o;
    o[0] = f2bf(v0.x); o[1] = f2bf(v0.y); o[2] = f2bf(v0.z); o[3] = f2bf(v0.w);
    o[4] = f2bf(v1.x); o[5] = f2bf(v1.y); o[6] = f2bf(v1.z); o[7] = f2bf(v1.w);
    int dst = (ch & ~31) | (c ^ (row & 7));
    *(u16v8*)(actA + dst * 8) = o;
  }
  __syncthreads();   // x staged + slab0/1 landed; vmcnt drained to 0

  // ---- phi: 12 stages, counted-vmcnt pipeline (no per-stage full drain) ----
  for (int s = 0; s < 12; ++s) {
    const int L = s >> 2, qd = s & 3;
    const ushort* cur = (s & 1) ? wq1 : wq0;
    // issue slab s+1 into other buffer; wait only for slab s (issued a full
    // stage ago, 2 loads/thread) -> vmcnt(2) leaves the fresh loads in flight
    if (s >= 1 && s < 11) {
      int sn = s + 1;
      int Ln = sn >> 2, qn = sn & 3;
      const ushort* wtn = (Ln == 0) ? wT1 : (Ln == 1) ? wT2 : wTa;
      ushort* dstb = (sn & 1) ? wq1 : wq0;
      LOADQ(wtn + qn * 16384, dstb);
      asm volatile("s_waitcnt vmcnt(2)" ::: "memory");
    } else {
      asm volatile("s_waitcnt vmcnt(0)" ::: "memory");
    }
    __builtin_amdgcn_s_barrier();   // slab s ready for all waves
    const ushort* aIn = (L & 1) ? actB : actA;
    ushort* aOut = (L & 1) ? actA : actB;
    const float* bias = (L == 0) ? p1b : (L == 1) ? p2b : ab;
    const int dorelu = (L < 2);
    if (wid < nrt * 4) {
      int rt = wid >> 2, ct = wid & 3;
      f32x4 acc = {0.f, 0.f, 0.f, 0.f};
#pragma unroll
      for (int kk = 0; kk < 8; ++kk) {
        int kc = (kk * 4 + q) ^ x7;
        bf16x8 a  = *(const bf16x8*)(aIn + ((rt * 16 + l15) * 32 + kc) * 8);
        bf16x8 bf = *(const bf16x8*)(cur + ((ct * 16 + l15) * 32 + kc) * 8);
        acc = __builtin_amdgcn_mfma_f32_16x16x32_bf16(a, bf, acc, 0, 0, 0);
      }
      int col = qd * 64 + ct * 16 + l15;
      float bv = bias[col];
#pragma unroll
      for (int i = 0; i < 4; ++i) {
        float vv = acc[i] + bv;
        if (dorelu) vv = fmaxf(vv, 0.f);
        int r = rt * 16 + q * 4 + i;
        int cc = (col >> 3) ^ (r & 7);
        aOut[(r * 32 + cc) * 8 + (col & 7)] = f2bf(vv);
      }
    }
    asm volatile("s_waitcnt lgkmcnt(0)" ::: "memory");  // act writes visible
    __builtin_amdgcn_s_barrier();   // cur readers done before next overwrite
  }
  // h = actA, s = actB (swizzled [64][256] bf16)

  // ---- attention: Gram(s) over 8 waves (4 row-tiles x 2 col-halves) ----
  if (tid < 256) colw[tid] = 0.f;
  __syncthreads();
  const int rt = wid & 3, h2 = wid >> 2;
  const bool liveW = (wid < 8) && (rt * 16 < n);
  float e0[4], e1[4];
  int cb0 = 0, cb1 = 0;
  if (liveW) {
    const char* stc = (const char*)actB;
    cb0 = (h2 * 2 + 0) * 16; cb1 = (h2 * 2 + 1) * 16;
    f32x4 acc0 = {0.f, 0.f, 0.f, 0.f}, acc1 = acc0;
    const int arow = rt * 16 + l15;
    if (cb0 < n) {
#pragma unroll
      for (int kk = 0; kk < 8; kk++) {
        int kc = ((kk * 4 + q) ^ x7) << 4;
        bf16x8 a  = *(const bf16x8*)(stc + arow * 512 + kc);
        bf16x8 b0 = *(const bf16x8*)(stc + (cb0 + l15) * 512 + kc);
        acc0 = __builtin_amdgcn_mfma_f32_16x16x32_bf16(a, b0, acc0, 0, 0, 0);
        if (cb1 < n) {
          bf16x8 b1 = *(const bf16x8*)(stc + (cb1 + l15) * 512 + kc);
          acc1 = __builtin_amdgcn_mfma_f32_16x16x32_bf16(a, b1, acc1, 0, 0, 0);
        }
      }
    }
    float pm[4], ps[4];
#pragma unroll
    for (int i = 0; i < 4; i++) {
      float mmx = (cb0 + l15 < n) ? acc0[i] : -1e30f;
      if (cb1 + l15 < n) mmx = fmaxf(mmx, acc1[i]);
      pm[i] = mmx;
    }
#pragma unroll
    for (int off = 1; off < 16; off <<= 1)
#pragma unroll
      for (int i = 0; i < 4; i++) pm[i] = fmaxf(pm[i], __shfl_xor(pm[i], off));
#pragma unroll
    for (int i = 0; i < 4; i++) {
      e0[i] = (cb0 + l15 < n) ? __expf(acc0[i] - pm[i]) : 0.f;
      e1[i] = (cb1 + l15 < n) ? __expf(acc1[i] - pm[i]) : 0.f;
      ps[i] = e0[i] + e1[i];
    }
#pragma unroll
    for (int off = 1; off < 16; off <<= 1)
#pragma unroll
      for (int i = 0; i < 4; i++) ps[i] += __shfl_xor(ps[i], off);
    if (l15 == 0) {
#pragma unroll
      for (int i = 0; i < 4; i++) {
        int row = rt * 16 + q * 4 + i;
        pmax[h2 * 64 + row] = pm[i];
        psum[h2 * 64 + row] = ps[i];
      }
    }
  }
  __syncthreads();
  if (tid < 128) {
    int h = tid >> 6, row = tid & 63;
    float m0 = pmax[row], m1 = pmax[64 + row];
    float m = fmaxf(m0, m1);
    float S = psum[row] * __expf(m0 - m) + psum[64 + row] * __expf(m1 - m);
    fct[h * 64 + row] = (S > 0.f) ? __expf(pmax[h * 64 + row] - m) / S : 0.f;
  }
  __syncthreads();
  if (liveW) {
    float cs0 = 0.f, cs1 = 0.f;
#pragma unroll
    for (int i = 0; i < 4; i++) {
      int row = rt * 16 + q * 4 + i;
      if (row < n) {
        float f = fct[h2 * 64 + row];
        cs0 += e0[i] * f;
        cs1 += e1[i] * f;
      }
    }
    cs0 += __shfl_xor(cs0, 16); cs0 += __shfl_xor(cs0, 32);
    cs1 += __shfl_xor(cs1, 16); cs1 += __shfl_xor(cs1, 32);
    if (lane < 16) {
      if (cb0 < n) atomicAdd(&colw[cb0 + l15], cs0);
      if (cb1 < n) atomicAdd(&colw[cb1 + l15], cs1);
    }
  }
  __syncthreads();

  // ---- aggregation: xa[c] = sum_j colw[j] * h[j][c], 4-way split ----
  {
    int c = tid & 255, qr = tid >> 8;
    float agg = 0.f;
    for (int jj = qr; jj < n; jj += 4) {
      int cc = (c >> 3) ^ (jj & 7);
      agg = fmaf(colw[jj], bf2f(actA[(jj * 32 + cc) * 8 + (c & 7)]), agg);
    }
    parts[qr * 256 + c] = agg;
  }
  __syncthreads();
  float* xa = pmax;   // reuse 256 f (pmax/psum dead after attn)
  if (tid < 256)
    xa[tid] = (parts[tid] + parts[256 + tid]) + (parts[512 + tid] + parts[768 + tid]);
  __syncthreads();

  // ---- rho GEMV: out[g] = relu(relu(xa@r1w+b1)@r2w+b2), 4-way k split ----
  {
    const int col = tid & 255, kq = tid >> 8;
    const int k0 = kq * 64;
    float a0 = 0.f, a1 = 0.f, a2 = 0.f, a3 = 0.f;
    const ushort* wp = rK1 + (size_t)k0 * HH + col;
#pragma unroll 4
    for (int k = 0; k < 64; k += 4) {
      a0 = fmaf(xa[k0 + k],     bf2f(wp[(size_t)(k)     * HH]), a0);
      a1 = fmaf(xa[k0 + k + 1], bf2f(wp[(size_t)(k + 1) * HH]), a1);
      a2 = fmaf(xa[k0 + k + 2], bf2f(wp[(size_t)(k + 2) * HH]), a2);
      a3 = fmaf(xa[k0 + k + 3], bf2f(wp[(size_t)(k + 3) * HH]), a3);
    }
    parts[kq * 256 + col] = (a0 + a1) + (a2 + a3);
    __syncthreads();
    if (tid < 256)
      colw[tid] = fmaxf(r1b[tid] + (parts[tid] + parts[256 + tid]) +
                        (parts[512 + tid] + parts[768 + tid]), 0.f);
    __syncthreads();
    a0 = a1 = a2 = a3 = 0.f;
    const ushort* wp2 = rK2 + (size_t)k0 * HH + col;
#pragma unroll 4
    for (int k = 0; k < 64; k += 4) {
      a0 = fmaf(colw[k0 + k],     bf2f(wp2[(size_t)(k)     * HH]), a0);
      a1 = fmaf(colw[k0 + k + 1], bf2f(wp2[(size_t)(k + 1) * HH]), a1);
      a2 = fmaf(colw[k0 + k + 2], bf2f(wp2[(size_t)(k + 2) * HH]), a2);
      a3 = fmaf(colw[k0 + k + 3], bf2f(wp2[(size_t)(k + 3) * HH]), a3);
    }
    parts[kq * 256 + col] = (a0 + a1) + (a2 + a3);
    __syncthreads();
    if (tid < 256)
      out[(size_t)g * HH + tid] = fmaxf(r2b[tid] + (parts[tid] + parts[256 + tid]) +
                                        (parts[512 + tid] + parts[768 + tid]), 0.f);
  }
}

// ---------------- launcher ----------------
extern "C" void kernel_launch(void* const* d_in, const int* in_sizes, int n_in,
                              void* d_out, int out_size, void* d_ws, size_t ws_size,
                              hipStream_t stream) {
  const float* x   = (const float*)d_in[0];
  const int* batch = (const int*)d_in[1];
  const float* aw  = (const float*)d_in[3];
  const float* ab  = (const float*)d_in[4];
  const float* p1w = (const float*)d_in[5];
  const float* p1b = (const float*)d_in[6];
  const float* p2w = (const float*)d_in[7];
  const float* p2b = (const float*)d_in[8];
  const float* r1w = (const float*)d_in[9];
  const float* r1b = (const float*)d_in[10];
  const float* r2w = (const float*)d_in[11];
  const float* r2b = (const float*)d_in[12];
  float* out = (float*)d_out;

  char* ws = (char*)d_ws;
  ushort* wT1 = (ushort*)(ws);            // 128 KB each
  ushort* wT2 = wT1 + 65536;
  ushort* wTa = wT2 + 65536;
  ushort* rK1 = wTa + 65536;
  ushort* rK2 = rK1 + 65536;

  k_prep<<<dim3(64), dim3(512), 0, stream>>>(p1w, p2w, aw, r1w, r2w,
                                             wT1, wT2, wTa, rK1, rK2);
  k_main<<<dim3(256), dim3(1024), 0, stream>>>(x, batch, ab, p1b, p2b, r1b, r2b,
                                               wT1, wT2, wTa, rK1, rK2, out);
}